// Round 16
// baseline (807.554 us; speedup 1.0000x reference)
//
#include <hip/hip_runtime.h>
#include <hip/hip_fp16.h>
#include <math.h>

// Problem constants
#define BB 2
#define SS 400
#define II 80
#define HH 128
#define FF 256          // 2*H
#define NN 401          // S+1
#define G4 512          // 4*H
#define MAXSEG 50
#define NCLS 50
#define KH 100          // rows of W1 / Wc1 / Wb1
#define KP 112          // KH padded to 7*16 for MFMA

// d_out layout (floats): scores | cls | bin | pred | prev
#define SCORES_OFF 0
#define CLS_OFF    (BB*NN*NN)
#define BIN_OFF    (CLS_OFF + BB*SS*NCLS)
#define PRED_OFF   (BIN_OFF + BB*SS*2)
#define PREV_OFF   (PRED_OFF + BB)

// workspace layout (float slots)
#define WS_GX      0                          // 4*S*512 = 819200 (dead after k_lstm_rec;
                                              // reused as scoresT 321602)
#define WS_RNN     (WS_GX + 4*SS*G4)          // B*S*F
#define WS_CUM     (WS_RNN + BB*SS*FF)        // B*N*F
#define WS_PXD     (WS_CUM + BB*NN*FF)        // B*N*KP
#define WS_PXE     (WS_PXD + BB*NN*KP)
#define WS_PART    (WS_PXE + BB*NN*KP)        // B*16*F
#define WS_W2P     (WS_PART + BB*16*FF)       // KP floats
#define WS_B1P     (WS_W2P + KP)              // KP floats
#define WS_WHP     (WS_B1P + KP)              // Wh f16: 2*512*128 halves = 65536 floats
#define WS_WFRAG   (WS_WHP + 65536)           // W1c bf16 frag-order: 28672 shorts

typedef __attribute__((ext_vector_type(8))) short short8;
typedef __attribute__((ext_vector_type(4))) float f32x4;
typedef _Float16 f16x2 __attribute__((ext_vector_type(2)));

__device__ __forceinline__ float prelu_f(float x, float a) {
    return x >= 0.f ? x : a * x;
}
__device__ __forceinline__ unsigned short f2bf(float x) {
    union { float f; unsigned u; } v; v.f = x;
    unsigned r = v.u + 0x7fffu + ((v.u >> 16) & 1u);   // RNE
    return (unsigned short)(r >> 16);
}
__device__ __forceinline__ float fast_sigmoid(float x) {
    return 1.f / (1.f + __expf(-x));
}
__device__ __forceinline__ float fast_tanh(float x) {
    return 1.f - 2.f / (1.f + __expf(2.f * x));
}
__device__ __forceinline__ float dot2f(unsigned w, unsigned h, float acc) {
#if __has_builtin(__builtin_amdgcn_fdot2)
    union { unsigned u; f16x2 h; } a, b; a.u = w; b.u = h;
    return __builtin_amdgcn_fdot2(a.h, b.h, acc, false);
#else
    union { unsigned u; _Float16 h[2]; } a, b; a.u = w; b.u = h;
    return acc + (float)a.h[0] * (float)b.h[0] + (float)a.h[1] * (float)b.h[1];
#endif
}
// LDS-only barrier (no vmcnt drain).
__device__ __forceinline__ void barrier_lds() {
    asm volatile("s_waitcnt lgkmcnt(0)\ns_barrier" ::: "memory");
}

// ---------------- K0: prep (W1c frag-order bf16 + W2/b1 pads + Wh f16) -----
__global__ void k_prep(const float* __restrict__ W1, const float* __restrict__ W2,
                       const float* __restrict__ b1,
                       const float* __restrict__ Wh_f, const float* __restrict__ Wh_b,
                       short* __restrict__ wfrag, float* __restrict__ w2p,
                       float* __restrict__ b1p, __half* __restrict__ whp) {
    int blk = blockIdx.x;
    int tid = threadIdx.x;           // 256
    if (blk < KP) {
        int k = blk;
        float w = (k < KH) ? W1[k * (3 * FF) + tid] : 0.f;
        int kt = k >> 4, l15 = k & 15;
        int ks = tid >> 5, quad = (tid >> 3) & 3, e = tid & 7;
        wfrag[((((kt * 8 + ks) * 4 + quad) * 16) + l15) * 8 + e] = (short)f2bf(w);
        if (tid == 0) {
            w2p[k] = (k < KH) ? W2[k] : 0.f;
            b1p[k] = (k < KH) ? b1[k] : 0.f;
        }
    } else {
        int g = blk - KP;            // 0..511
        int dir = tid >> 7, k = tid & 127;
        const float* Wh = dir ? Wh_b : Wh_f;
        whp[(dir * G4 + g) * HH + k] = (__half)Wh[g * HH + k];
    }
}

// ---------------- K1: gx[db][t][g] = b[g] + x[b, xt, :] . Wi[g, :] ---------
__global__ void k_lstm_pre(const float* __restrict__ x,
                           const float* __restrict__ Wi_f, const float* __restrict__ b_f,
                           const float* __restrict__ Wi_b, const float* __restrict__ b_b,
                           float* __restrict__ gx) {
    int blk = blockIdx.x;          // db*S + t
    int t = blk % SS;
    int db = blk / SS;             // dir*2 + b
    int b = db & 1, dir = db >> 1;
    const float* Wi = dir ? Wi_b : Wi_f;
    const float* bias = dir ? b_b : b_f;
    int xt = dir ? (SS - 1 - t) : t;

    __shared__ __align__(16) float xr[II];
    int tid = threadIdx.x;
    if (tid < II) xr[tid] = x[(b * SS + xt) * II + tid];
    __syncthreads();

    for (int g = tid; g < G4; g += 256) {
        const float* w = Wi + g * II;
        float acc = bias[g];
#pragma unroll
        for (int i = 0; i < II; i += 4) {
            float4 w4 = *(const float4*)(w + i);
            acc += w4.x * xr[i] + w4.y * xr[i + 1] + w4.z * xr[i + 2] + w4.w * xr[i + 3];
        }
        gx[(db * SS + t) * G4 + g] = acc;
    }
}

// ---------------- K2: recurrent LSTM (measured floor ~275 µs) --------------
__global__ __launch_bounds__(512, 2)
void k_lstm_rec(const __half* __restrict__ whp, const float* __restrict__ gx,
                float* __restrict__ rnn_out) {
    int db = blockIdx.x;
    int b = db & 1, dir = db >> 1;
    int tid = threadIdx.x;          // = gate id g

    uint4 w[16];
    {
        const uint4* wp = (const uint4*)(whp + (dir * G4 + tid) * HH);
#pragma unroll
        for (int c = 0; c < 16; ++c) w[c] = wp[c];
    }

    __shared__ __align__(16) __half hsf[2][144];   // 128 h + pad
    __shared__ float gsh[G4];
    for (int i = tid; i < 2 * 144; i += 512) (&hsf[0][0])[i] = (__half)0.f;
    float c_state = 0.f;
    __syncthreads();

    const float* gxp = gx + db * SS * G4;
    float gcur = gxp[tid];                     // prefetch step 0
    int pb = 0;
    for (int step = 0; step < SS; ++step) {
        float gnext = (step + 1 < SS) ? gxp[(step + 1) * G4 + tid] : 0.f;
        const uint4* hp = (const uint4*)(&hsf[pb][0]);
        float a0 = 0.f, a1 = 0.f, a2 = 0.f, a3 = 0.f;
#pragma unroll
        for (int c = 0; c < 16; ++c) {
            uint4 hq = hp[c];
            a0 = dot2f(w[c].x, hq.x, a0);
            a1 = dot2f(w[c].y, hq.y, a1);
            a2 = dot2f(w[c].z, hq.z, a2);
            a3 = dot2f(w[c].w, hq.w, a3);
        }
        gsh[tid] = (a0 + a1) + (a2 + a3) + gcur;
        barrier_lds();
        if (tid < HH) {
            float gi = gsh[tid], gf = gsh[HH + tid];
            float gg = gsh[2 * HH + tid], go = gsh[3 * HH + tid];
            c_state = fast_sigmoid(gf) * c_state + fast_sigmoid(gi) * fast_tanh(gg);
            float h = fast_sigmoid(go) * fast_tanh(c_state);
            hsf[pb ^ 1][tid] = (__half)h;
            int xt = dir ? (SS - 1 - step) : step;
            rnn_out[(b * SS + xt) * FF + dir * HH + tid] = h;
        }
        barrier_lds();
        pb ^= 1;
        gcur = gnext;
    }
}

// ---------------- K3: cumsum over time (3 passes) --------------------------
#define CHUNK 25
#define NCH 16
__global__ void k_cum_part(const float* __restrict__ rnn, float* __restrict__ part) {
    int blk = blockIdx.x;           // b*NCH + c
    int c = blk % NCH, b = blk / NCH;
    int f = threadIdx.x;
    float s = 0.f;
    for (int r = 0; r < CHUNK; ++r) s += rnn[(b * SS + c * CHUNK + r) * FF + f];
    part[blk * FF + f] = s;
}
__global__ void k_cum_off(float* __restrict__ part) {
    int b = blockIdx.x;
    int f = threadIdx.x;
    float run = 0.f;
    for (int c = 0; c < NCH; ++c) {
        int idx = (b * NCH + c) * FF + f;
        float tmp = part[idx];
        part[idx] = run;
        run += tmp;
    }
}
__global__ void k_cum_write(const float* __restrict__ rnn, const float* __restrict__ part,
                            float* __restrict__ cum) {
    int blk = blockIdx.x;           // b*NCH + c
    int c = blk % NCH, b = blk / NCH;
    int f = threadIdx.x;
    float run = part[blk * FF + f];
    cum[(b * NN + c * CHUNK) * FF + f] = run;
    for (int idx = 1; idx <= CHUNK; ++idx) {
        run += rnn[(b * SS + c * CHUNK + idx - 1) * FF + f];
        cum[(b * NN + c * CHUNK + idx) * FF + f] = run;
    }
}

// ---------------- K4: fused pxd/pxe (blk<802) + cls/bin heads (blk>=802) ---
__global__ void k_pxde_heads(const float* __restrict__ rnn, const float* __restrict__ W1,
                             const float* __restrict__ a1p,
                             float* __restrict__ pxd, float* __restrict__ pxe,
                             const float* __restrict__ ac1p, const float* __restrict__ Wc1,
                             const float* __restrict__ bc1, const float* __restrict__ ac2p,
                             const float* __restrict__ Wc2, const float* __restrict__ bc2,
                             const float* __restrict__ ab1p, const float* __restrict__ Wb1,
                             const float* __restrict__ bb1, const float* __restrict__ ab2p,
                             const float* __restrict__ Wb2, const float* __restrict__ bb2,
                             float* __restrict__ cls_out, float* __restrict__ bin_out) {
    int blk = blockIdx.x;
    int tid = threadIdx.x;
    if (blk < BB * NN) {
        int n = blk % NN, b = blk / NN;
        float a1 = a1p[0];
        __shared__ __align__(16) float px[FF];
        float rv = (n == 0) ? 0.f : rnn[(b * SS + n - 1) * FF + tid];
        px[tid] = prelu_f(rv, a1);
        __syncthreads();

        if (tid < KH) {
            const float* w = W1 + tid * (3 * FF) + FF;    // W1d row
            float acc = 0.f;
#pragma unroll 8
            for (int f = 0; f < FF; f += 4) {
                float4 w4 = *(const float4*)(w + f);
                acc += w4.x * px[f] + w4.y * px[f + 1] + w4.z * px[f + 2] + w4.w * px[f + 3];
            }
            pxd[blk * KP + tid] = acc;
        } else if (tid >= KH && tid < KP) {
            pxd[blk * KP + tid] = 0.f;
        } else if (tid >= 128 && tid < 128 + KH) {
            int k = tid - 128;
            const float* w = W1 + k * (3 * FF) + 2 * FF;  // W1e row
            float acc = 0.f;
#pragma unroll 8
            for (int f = 0; f < FF; f += 4) {
                float4 w4 = *(const float4*)(w + f);
                acc += w4.x * px[f] + w4.y * px[f + 1] + w4.z * px[f + 2] + w4.w * px[f + 3];
            }
            pxe[blk * KP + k] = acc;
        } else if (tid >= 128 + KH && tid < 128 + KP) {
            pxe[blk * KP + (tid - 128)] = 0.f;
        }
    } else {
        int hb = blk - BB * NN;         // b*S + t
        int ts = hb % SS, b = hb / SS;
        __shared__ __align__(16) float prc[FF], prb[FF];
        __shared__ __align__(16) float uc[KH], ub[KH];
        float ac1 = ac1p[0], ab1 = ab1p[0];
        float rv = rnn[(b * SS + ts) * FF + tid];
        prc[tid] = prelu_f(rv, ac1);
        prb[tid] = prelu_f(rv, ab1);
        __syncthreads();
        if (tid < KH) {
            const float* wc = Wc1 + tid * FF;
            float ac = 0.f;
#pragma unroll 8
            for (int f = 0; f < FF; f += 4) {
                float4 c4 = *(const float4*)(wc + f);
                ac += c4.x * prc[f] + c4.y * prc[f + 1] + c4.z * prc[f + 2] + c4.w * prc[f + 3];
            }
            uc[tid] = prelu_f(ac + bc1[tid], ac2p[0]);
        } else if (tid >= 128 && tid < 128 + KH) {
            int k = tid - 128;
            const float* wb = Wb1 + k * FF;
            float ab = 0.f;
#pragma unroll 8
            for (int f = 0; f < FF; f += 4) {
                float4 b4 = *(const float4*)(wb + f);
                ab += b4.x * prb[f] + b4.y * prb[f + 1] + b4.z * prb[f + 2] + b4.w * prb[f + 3];
            }
            ub[k] = prelu_f(ab + bb1[k], ab2p[0]);
        }
        __syncthreads();
        if (tid < NCLS) {
            const float* w = Wc2 + tid * KH;
            float acc = bc2[tid];
#pragma unroll
            for (int q = 0; q < KH; q += 4) {
                float4 w4 = *(const float4*)(w + q);
                acc += w4.x * uc[q] + w4.y * uc[q + 1] + w4.z * uc[q + 2] + w4.w * uc[q + 3];
            }
            cls_out[(b * SS + ts) * NCLS + tid] = acc;
        }
        if (tid >= 64 && tid < 66) {
            int o = tid - 64;
            const float* w = Wb2 + o * KH;
            float acc = bb2[o];
#pragma unroll
            for (int q = 0; q < KH; q += 4) {
                float4 w4 = *(const float4*)(w + q);
                acc += w4.x * ub[q] + w4.y * ub[q + 1] + w4.z * ub[q + 2] + w4.w * ub[q + 3];
            }
            bin_out[(b * SS + ts) * 2 + o] = acc;
        }
    }
}

// ---------------- K5: scores v4 — LDS-staged pxe/pxd epilogue --------------
// v3 epilogue did 16 global GATHERS per block (lane-varying jc×kout). Now the
// 32x112 pxe tile + 2x112 pxd rows are staged coalesced into LDS during the
// A-build phase (same barrier); epilogue reads LDS.
#define JT 32
#define JTILES 13
#define NP2 201
#define AP 272          // A-tile row stride in shorts
#define PEP 116         // pxe tile row stride in floats
__global__ __launch_bounds__(256, 2)
void k_scores(const float* __restrict__ cum,
              const short* __restrict__ wfrag,
              const float* __restrict__ pxd, const float* __restrict__ pxe,
              const float* __restrict__ b1p, const float* __restrict__ w2p,
              const float* __restrict__ b2p,
              const float* __restrict__ a1p, const float* __restrict__ a2p,
              float* __restrict__ scores, float* __restrict__ scoresT) {
    int blk = blockIdx.x;
    int jt = blk % JTILES;
    int ipair = (blk / JTILES) % NP2;
    int b = blk / (JTILES * NP2);
    int tid = threadIdx.x;
    float a1 = a1p[0], a2 = a2p[0];
    int jbase = jt * JT;
    int i0 = ipair * 2;
    int i1 = i0 + 1;
    bool has_i1 = (i1 <= SS);
    int i1c = has_i1 ? i1 : i0;

    __shared__ __align__(16) float cish[2][FF];
    __shared__ __align__(16) short dth[2][JT][AP];
    __shared__ float red[2][4][JT];
    __shared__ float pxesh[JT][PEP];
    __shared__ float pxdsh[2][PEP];

    cish[0][tid] = cum[(b * NN + i0) * FF + tid];
    cish[1][tid] = cum[(b * NN + i1c) * FF + tid];
    // stage pxd rows (coalesced)
    if (tid < 2 * KP) {
        int ii = tid / KP, col = tid % KP;
        int iv = ii ? i1c : i0;
        pxdsh[ii][col] = pxd[(b * NN + iv) * KP + col];
    }
    __syncthreads();

    // ---- build both A tiles from ONE cum-row read + stage pxe tile
    {
        int row = tid >> 3;
        int fb = (tid & 7) * 32;
        int jg = jbase + row;
        int jc = (jg <= SS) ? jg : SS;
        const float* cj = cum + (b * NN + jc) * FF + fb;
        float4 v[8];
#pragma unroll
        for (int c8 = 0; c8 < 4; ++c8) {
            v[2 * c8] = *(const float4*)(cj + c8 * 8);
            v[2 * c8 + 1] = *(const float4*)(cj + c8 * 8 + 4);
        }
#pragma unroll
        for (int ii = 0; ii < 2; ++ii) {
            const float* cio = &cish[ii][0];
#pragma unroll
            for (int c8 = 0; c8 < 4; ++c8) {
                float dv[8] = { v[2*c8].x, v[2*c8].y, v[2*c8].z, v[2*c8].w,
                                v[2*c8+1].x, v[2*c8+1].y, v[2*c8+1].z, v[2*c8+1].w };
                union { short8 s; unsigned short u[8]; } h8;
#pragma unroll
                for (int e = 0; e < 8; ++e) {
                    float d = prelu_f(dv[e] - cio[fb + c8 * 8 + e], a1);
                    h8.u[e] = f2bf(d);
                }
                *(short8*)(&dth[ii][row][fb + c8 * 8]) = h8.s;
            }
        }
        // pxe tile: 32 rows x 112 cols, coalesced
        for (int idx = tid; idx < JT * KP; idx += 256) {
            int r = idx / KP, col = idx % KP;
            int jg2 = jbase + r;
            int jc2 = (jg2 <= SS) ? jg2 : SS;
            pxesh[r][col] = pxe[(b * NN + jc2) * KP + col];
        }
    }
    __syncthreads();

    int lane = tid & 63;
    int wv = tid >> 6;
    int quad = lane >> 4;
    int l15 = lane & 15;
    int kt0 = wv * 2, kt1 = wv * 2 + 1;
    bool has1 = (kt1 < 7);

    const short8* wf = (const short8*)wfrag;
    f32x4 acc[2][2][2];
#pragma unroll
    for (int ii = 0; ii < 2; ++ii)
#pragma unroll
        for (int mt = 0; mt < 2; ++mt)
#pragma unroll
            for (int kk = 0; kk < 2; ++kk) acc[ii][mt][kk] = (f32x4){0.f,0.f,0.f,0.f};

#pragma unroll
    for (int ks = 0; ks < 8; ++ks) {
        short8 b0 = wf[((kt0 * 8 + ks) * 4 + quad) * 16 + l15];
        short8 b1v = has1 ? wf[((kt1 * 8 + ks) * 4 + quad) * 16 + l15] : b0;
#pragma unroll
        for (int ii = 0; ii < 2; ++ii) {
#pragma unroll
            for (int mt = 0; mt < 2; ++mt) {
                short8 a = *(const short8*)(&dth[ii][mt * 16 + l15][ks * 32 + quad * 8]);
                acc[ii][mt][0] = __builtin_amdgcn_mfma_f32_16x16x32_bf16(a, b0, acc[ii][mt][0], 0, 0, 0);
                if (has1)
                    acc[ii][mt][1] = __builtin_amdgcn_mfma_f32_16x16x32_bf16(a, b1v, acc[ii][mt][1], 0, 0, 0);
            }
        }
    }

    int kout0 = kt0 * 16 + l15;
    int kout1 = has1 ? (kt1 * 16 + l15) : 0;
    float bb0 = b1p[kout0], bb1v = b1p[kout1];
    float w20 = w2p[kout0];
    float w21 = has1 ? w2p[kout1] : 0.f;

#pragma unroll
    for (int ii = 0; ii < 2; ++ii) {
        float pd0 = pxdsh[ii][kout0];
        float pd1 = pxdsh[ii][kout1];
#pragma unroll
        for (int mt = 0; mt < 2; ++mt) {
#pragma unroll
            for (int r = 0; r < 4; ++r) {
                int m = mt * 16 + quad * 4 + r;
                float pe0 = pxesh[m][kout0];
                float pe1 = pxesh[m][kout1];
                float h0 = acc[ii][mt][0][r] + pd0 + pe0 + bb0;
                float s = w20 * prelu_f(h0, a2);
                float h1 = acc[ii][mt][1][r] + pd1 + pe1 + bb1v;
                s += w21 * prelu_f(h1, a2);
                s += __shfl_xor(s, 1);
                s += __shfl_xor(s, 2);
                s += __shfl_xor(s, 4);
                s += __shfl_xor(s, 8);
                if (l15 == 0) red[ii][wv][m] = s;
            }
        }
    }
    __syncthreads();
    if (tid < 2 * JT) {
        int ii = tid >> 5;
        int jl = tid & 31;
        int jg = jbase + jl;
        int iv = ii ? i1 : i0;
        if (jg <= SS && (ii == 0 || has_i1)) {
            float tot = red[ii][0][jl] + red[ii][1][jl] + red[ii][2][jl] + red[ii][3][jl] + b2p[0];
            scores[(b * NN + iv) * NN + jg] = tot;
            scoresT[(b * NN + jg) * NN + iv] = tot;
        }
    }
}

// ---------------- K7: DP segment search — 4-deep column pipeline -----------
// The serial loop's column load is a cross-XCD L2 miss (~500-900 cyc); with
// 1-deep prefetch the chain (~150 cyc) can't hide it. 4 columns in flight
// (static rotating registers via 4x unroll) cuts exposed latency ~4x.
__global__ void k_dp(const float* __restrict__ scoresT, const int* __restrict__ lengths,
                     float* __restrict__ predF, float* __restrict__ prevF) {
    int b = blockIdx.x;
    int lane = threadIdx.x;          // 64 threads = 1 wave
    int len = lengths[b];
    if (lane == 0) prevF[b * NN] = 0.f;

    float blr = 0.f;                 // best[lo + lane]
    float predv = 0.f;

#define LOADCOL(ii) \
    ( ((ii) <= SS && lane < ((ii) - (((ii) > MAXSEG) ? ((ii) - MAXSEG) : 0))) \
        ? scoresT[(b * NN + (ii)) * NN + ((((ii) > MAXSEG) ? ((ii) - MAXSEG) : 0)) + lane] : 0.f )

    float buf0 = LOADCOL(1);
    float buf1 = LOADCOL(2);
    float buf2 = LOADCOL(3);
    float buf3 = LOADCOL(4);

#define DP_STEP(I, BUF) do {                                                  \
        int lo_ = ((I) > MAXSEG) ? ((I) - MAXSEG) : 0;                        \
        int cnt_ = (I) - lo_;                                                 \
        float cand = (lane < cnt_) ? blr + BUF : -INFINITY;                   \
        int idx = lo_ + lane;                                                 \
        for (int off = 32; off; off >>= 1) {                                  \
            float vo = __shfl_down(cand, off);                                \
            int io = __shfl_down(idx, off);                                   \
            if (vo > cand || (vo == cand && io < idx)) { cand = vo; idx = io; } \
        }                                                                     \
        float m_ = __shfl(cand, 0);                                           \
        if (lane == 0) {                                                      \
            prevF[b * NN + (I)] = (float)idx;                                 \
            if ((I) == len) predv = m_;                                       \
        }                                                                     \
        int lon_ = ((I) + 1 > MAXSEG) ? ((I) + 1 - MAXSEG) : 0;               \
        if (lon_ != lo_) blr = __shfl_down(blr, 1);                           \
        if (lane == (I) - lon_) blr = m_;                                     \
    } while (0)

    for (int i = 1; i <= SS; i += 4) {
        DP_STEP(i, buf0);     buf0 = LOADCOL(i + 4);
        DP_STEP(i + 1, buf1); buf1 = LOADCOL(i + 5);
        DP_STEP(i + 2, buf2); buf2 = LOADCOL(i + 6);
        DP_STEP(i + 3, buf3); buf3 = LOADCOL(i + 7);
    }
#undef DP_STEP
#undef LOADCOL
    if (lane == 0) predF[b] = predv;
}

// ---------------- launch ---------------------------------------------------
extern "C" void kernel_launch(void* const* d_in, const int* in_sizes, int n_in,
                              void* d_out, int out_size, void* d_ws, size_t ws_size,
                              hipStream_t stream) {
    const float* x    = (const float*)d_in[0];
    const int* lengths= (const int*)d_in[1];
    const float* Wi_f = (const float*)d_in[2];
    const float* Wh_f = (const float*)d_in[3];
    const float* b_f  = (const float*)d_in[4];
    const float* Wi_b = (const float*)d_in[5];
    const float* Wh_b = (const float*)d_in[6];
    const float* b_b  = (const float*)d_in[7];
    const float* a1   = (const float*)d_in[8];
    const float* W1   = (const float*)d_in[9];
    const float* b1   = (const float*)d_in[10];
    const float* a2   = (const float*)d_in[11];
    const float* W2   = (const float*)d_in[12];
    const float* b2   = (const float*)d_in[13];
    const float* ac1  = (const float*)d_in[14];
    const float* Wc1  = (const float*)d_in[15];
    const float* bc1  = (const float*)d_in[16];
    const float* ac2  = (const float*)d_in[17];
    const float* Wc2  = (const float*)d_in[18];
    const float* bc2  = (const float*)d_in[19];
    const float* ab1  = (const float*)d_in[20];
    const float* Wb1  = (const float*)d_in[21];
    const float* bb1  = (const float*)d_in[22];
    const float* ab2  = (const float*)d_in[23];
    const float* Wb2  = (const float*)d_in[24];
    const float* bb2  = (const float*)d_in[25];

    float* out = (float*)d_out;
    float* scores = out + SCORES_OFF;
    float* cls    = out + CLS_OFF;
    float* bin    = out + BIN_OFF;
    float* pred   = out + PRED_OFF;
    float* prev   = out + PREV_OFF;

    float* ws   = (float*)d_ws;
    float* gx   = ws + WS_GX;
    float* scoresT = ws + WS_GX;     // reuse: gx dead after k_lstm_rec
    float* rnn  = ws + WS_RNN;
    float* cum  = ws + WS_CUM;
    float* pxd  = ws + WS_PXD;
    float* pxe  = ws + WS_PXE;
    float* part = ws + WS_PART;
    float* w2p  = ws + WS_W2P;
    float* b1p  = ws + WS_B1P;
    __half* whp = (__half*)(ws + WS_WHP);
    short* wfrag= (short*)(ws + WS_WFRAG);

    k_prep<<<KP + G4, 256, 0, stream>>>(W1, W2, b1, Wh_f, Wh_b, wfrag, w2p, b1p, whp);
    k_lstm_pre<<<4 * SS, 256, 0, stream>>>(x, Wi_f, b_f, Wi_b, b_b, gx);
    k_lstm_rec<<<4, 512, 0, stream>>>(whp, gx, rnn);
    k_cum_part<<<BB * NCH, FF, 0, stream>>>(rnn, part);
    k_cum_off<<<BB, FF, 0, stream>>>(part);
    k_cum_write<<<BB * NCH, FF, 0, stream>>>(rnn, part, cum);
    k_pxde_heads<<<BB * NN + BB * SS, 256, 0, stream>>>(rnn, W1, a1, pxd, pxe,
                                                        ac1, Wc1, bc1, ac2, Wc2, bc2,
                                                        ab1, Wb1, bb1, ab2, Wb2, bb2,
                                                        cls, bin);
    k_scores<<<BB * NP2 * JTILES, 256, 0, stream>>>(cum, wfrag, pxd, pxe, b1p, w2p, b2,
                                                    a1, a2, scores, scoresT);
    k_dp<<<BB, 64, 0, stream>>>(scoresT, lengths, pred, prev);
}

// Round 17
// 790.358 us; speedup vs baseline: 1.0218x; 1.0218x over previous
//
#include <hip/hip_runtime.h>
#include <hip/hip_fp16.h>
#include <math.h>

// Problem constants
#define BB 2
#define SS 400
#define II 80
#define HH 128
#define FF 256          // 2*H
#define NN 401          // S+1
#define G4 512          // 4*H
#define MAXSEG 50
#define NCLS 50
#define KH 100          // rows of W1 / Wc1 / Wb1
#define KP 112          // KH padded to 7*16 for MFMA

// d_out layout (floats): scores | cls | bin | pred | prev
#define SCORES_OFF 0
#define CLS_OFF    (BB*NN*NN)
#define BIN_OFF    (CLS_OFF + BB*SS*NCLS)
#define PRED_OFF   (BIN_OFF + BB*SS*2)
#define PREV_OFF   (PRED_OFF + BB)

// workspace layout (float slots)
#define WS_GX      0                          // 4*S*512 = 819200 (dead after k_lstm_rec;
                                              // reused as scoresT 321602)
#define WS_RNN     (WS_GX + 4*SS*G4)          // B*S*F
#define WS_CUM     (WS_RNN + BB*SS*FF)        // B*N*F
#define WS_PXD     (WS_CUM + BB*NN*FF)        // B*N*KP
#define WS_PXE     (WS_PXD + BB*NN*KP)
#define WS_PART    (WS_PXE + BB*NN*KP)        // B*16*F
#define WS_W2P     (WS_PART + BB*16*FF)       // KP floats
#define WS_B1P     (WS_W2P + KP)              // KP floats
#define WS_WHP     (WS_B1P + KP)              // Wh f16: 2*512*128 halves = 65536 floats
#define WS_WFRAG   (WS_WHP + 65536)           // W1c bf16 frag-order: 28672 shorts

typedef __attribute__((ext_vector_type(8))) short short8;
typedef __attribute__((ext_vector_type(4))) float f32x4;
typedef _Float16 f16x2 __attribute__((ext_vector_type(2)));

__device__ __forceinline__ float prelu_f(float x, float a) {
    return x >= 0.f ? x : a * x;
}
__device__ __forceinline__ unsigned short f2bf(float x) {
    union { float f; unsigned u; } v; v.f = x;
    unsigned r = v.u + 0x7fffu + ((v.u >> 16) & 1u);   // RNE
    return (unsigned short)(r >> 16);
}
__device__ __forceinline__ float fast_sigmoid(float x) {
    return 1.f / (1.f + __expf(-x));
}
__device__ __forceinline__ float fast_tanh(float x) {
    return 1.f - 2.f / (1.f + __expf(2.f * x));
}
__device__ __forceinline__ float dot2f(unsigned w, unsigned h, float acc) {
#if __has_builtin(__builtin_amdgcn_fdot2)
    union { unsigned u; f16x2 h; } a, b; a.u = w; b.u = h;
    return __builtin_amdgcn_fdot2(a.h, b.h, acc, false);
#else
    union { unsigned u; _Float16 h[2]; } a, b; a.u = w; b.u = h;
    return acc + (float)a.h[0] * (float)b.h[0] + (float)a.h[1] * (float)b.h[1];
#endif
}
// LDS-only barrier (no vmcnt drain).
__device__ __forceinline__ void barrier_lds() {
    asm volatile("s_waitcnt lgkmcnt(0)\ns_barrier" ::: "memory");
}

// ---------------- K1: fused prep (blk<624) + gx precompute (blk>=624) ------
#define PREPBLKS (KP + G4)
__global__ void k_lstm_pre(const float* __restrict__ x,
                           const float* __restrict__ Wi_f, const float* __restrict__ b_f,
                           const float* __restrict__ Wi_b, const float* __restrict__ b_b,
                           float* __restrict__ gx,
                           const float* __restrict__ W1, const float* __restrict__ W2,
                           const float* __restrict__ b1,
                           const float* __restrict__ Wh_f, const float* __restrict__ Wh_b,
                           short* __restrict__ wfrag, float* __restrict__ w2p,
                           float* __restrict__ b1p, __half* __restrict__ whp) {
    int blk0 = blockIdx.x;
    int tid = threadIdx.x;
    if (blk0 < PREPBLKS) {
        if (blk0 < KP) {
            int k = blk0;
            float w = (k < KH) ? W1[k * (3 * FF) + tid] : 0.f;
            int kt = k >> 4, l15 = k & 15;
            int ks = tid >> 5, quad = (tid >> 3) & 3, e = tid & 7;
            wfrag[((((kt * 8 + ks) * 4 + quad) * 16) + l15) * 8 + e] = (short)f2bf(w);
            if (tid == 0) {
                w2p[k] = (k < KH) ? W2[k] : 0.f;
                b1p[k] = (k < KH) ? b1[k] : 0.f;
            }
        } else {
            int g = blk0 - KP;           // 0..511
            int dir = tid >> 7, k = tid & 127;
            const float* Wh = dir ? Wh_b : Wh_f;
            whp[(dir * G4 + g) * HH + k] = (__half)Wh[g * HH + k];
        }
        return;
    }
    int blk = blk0 - PREPBLKS;         // db*S + t
    int t = blk % SS;
    int db = blk / SS;                 // dir*2 + b
    int b = db & 1, dir = db >> 1;
    const float* Wi = dir ? Wi_b : Wi_f;
    const float* bias = dir ? b_b : b_f;
    int xt = dir ? (SS - 1 - t) : t;

    __shared__ __align__(16) float xr[II];
    if (tid < II) xr[tid] = x[(b * SS + xt) * II + tid];
    __syncthreads();

    for (int g = tid; g < G4; g += 256) {
        const float* w = Wi + g * II;
        float acc = bias[g];
#pragma unroll
        for (int i = 0; i < II; i += 4) {
            float4 w4 = *(const float4*)(w + i);
            acc += w4.x * xr[i] + w4.y * xr[i + 1] + w4.z * xr[i + 2] + w4.w * xr[i + 3];
        }
        gx[(db * SS + t) * G4 + g] = acc;
    }
}

// ---------------- K2: recurrent LSTM (measured floor ~275 µs) --------------
__global__ __launch_bounds__(512, 2)
void k_lstm_rec(const __half* __restrict__ whp, const float* __restrict__ gx,
                float* __restrict__ rnn_out) {
    int db = blockIdx.x;
    int b = db & 1, dir = db >> 1;
    int tid = threadIdx.x;          // = gate id g

    uint4 w[16];
    {
        const uint4* wp = (const uint4*)(whp + (dir * G4 + tid) * HH);
#pragma unroll
        for (int c = 0; c < 16; ++c) w[c] = wp[c];
    }

    __shared__ __align__(16) __half hsf[2][144];   // 128 h + pad
    __shared__ float gsh[G4];
    for (int i = tid; i < 2 * 144; i += 512) (&hsf[0][0])[i] = (__half)0.f;
    float c_state = 0.f;
    __syncthreads();

    const float* gxp = gx + db * SS * G4;
    float gcur = gxp[tid];                     // prefetch step 0
    int pb = 0;
    for (int step = 0; step < SS; ++step) {
        float gnext = (step + 1 < SS) ? gxp[(step + 1) * G4 + tid] : 0.f;
        const uint4* hp = (const uint4*)(&hsf[pb][0]);
        float a0 = 0.f, a1 = 0.f, a2 = 0.f, a3 = 0.f;
#pragma unroll
        for (int c = 0; c < 16; ++c) {
            uint4 hq = hp[c];
            a0 = dot2f(w[c].x, hq.x, a0);
            a1 = dot2f(w[c].y, hq.y, a1);
            a2 = dot2f(w[c].z, hq.z, a2);
            a3 = dot2f(w[c].w, hq.w, a3);
        }
        gsh[tid] = (a0 + a1) + (a2 + a3) + gcur;
        barrier_lds();
        if (tid < HH) {
            float gi = gsh[tid], gf = gsh[HH + tid];
            float gg = gsh[2 * HH + tid], go = gsh[3 * HH + tid];
            c_state = fast_sigmoid(gf) * c_state + fast_sigmoid(gi) * fast_tanh(gg);
            float h = fast_sigmoid(go) * fast_tanh(c_state);
            hsf[pb ^ 1][tid] = (__half)h;
            int xt = dir ? (SS - 1 - step) : step;
            rnn_out[(b * SS + xt) * FF + dir * HH + tid] = h;
        }
        barrier_lds();
        pb ^= 1;
        gcur = gnext;
    }
}

// ---------------- K3: cumsum over time (3 passes) --------------------------
#define CHUNK 25
#define NCH 16
__global__ void k_cum_part(const float* __restrict__ rnn, float* __restrict__ part) {
    int blk = blockIdx.x;           // b*NCH + c
    int c = blk % NCH, b = blk / NCH;
    int f = threadIdx.x;
    float s = 0.f;
    for (int r = 0; r < CHUNK; ++r) s += rnn[(b * SS + c * CHUNK + r) * FF + f];
    part[blk * FF + f] = s;
}
__global__ void k_cum_off(float* __restrict__ part) {
    int b = blockIdx.x;
    int f = threadIdx.x;
    float run = 0.f;
    for (int c = 0; c < NCH; ++c) {
        int idx = (b * NCH + c) * FF + f;
        float tmp = part[idx];
        part[idx] = run;
        run += tmp;
    }
}
__global__ void k_cum_write(const float* __restrict__ rnn, const float* __restrict__ part,
                            float* __restrict__ cum) {
    int blk = blockIdx.x;           // b*NCH + c
    int c = blk % NCH, b = blk / NCH;
    int f = threadIdx.x;
    float run = part[blk * FF + f];
    cum[(b * NN + c * CHUNK) * FF + f] = run;
    for (int idx = 1; idx <= CHUNK; ++idx) {
        run += rnn[(b * SS + c * CHUNK + idx - 1) * FF + f];
        cum[(b * NN + c * CHUNK + idx) * FF + f] = run;
    }
}

// ---------------- K4: fused pxd/pxe (blk<802) + cls/bin heads (blk>=802) ---
__global__ void k_pxde_heads(const float* __restrict__ rnn, const float* __restrict__ W1,
                             const float* __restrict__ a1p,
                             float* __restrict__ pxd, float* __restrict__ pxe,
                             const float* __restrict__ ac1p, const float* __restrict__ Wc1,
                             const float* __restrict__ bc1, const float* __restrict__ ac2p,
                             const float* __restrict__ Wc2, const float* __restrict__ bc2,
                             const float* __restrict__ ab1p, const float* __restrict__ Wb1,
                             const float* __restrict__ bb1, const float* __restrict__ ab2p,
                             const float* __restrict__ Wb2, const float* __restrict__ bb2,
                             float* __restrict__ cls_out, float* __restrict__ bin_out) {
    int blk = blockIdx.x;
    int tid = threadIdx.x;
    if (blk < BB * NN) {
        int n = blk % NN, b = blk / NN;
        float a1 = a1p[0];
        __shared__ __align__(16) float px[FF];
        float rv = (n == 0) ? 0.f : rnn[(b * SS + n - 1) * FF + tid];
        px[tid] = prelu_f(rv, a1);
        __syncthreads();

        if (tid < KH) {
            const float* w = W1 + tid * (3 * FF) + FF;    // W1d row
            float acc = 0.f;
#pragma unroll 8
            for (int f = 0; f < FF; f += 4) {
                float4 w4 = *(const float4*)(w + f);
                acc += w4.x * px[f] + w4.y * px[f + 1] + w4.z * px[f + 2] + w4.w * px[f + 3];
            }
            pxd[blk * KP + tid] = acc;
        } else if (tid >= KH && tid < KP) {
            pxd[blk * KP + tid] = 0.f;
        } else if (tid >= 128 && tid < 128 + KH) {
            int k = tid - 128;
            const float* w = W1 + k * (3 * FF) + 2 * FF;  // W1e row
            float acc = 0.f;
#pragma unroll 8
            for (int f = 0; f < FF; f += 4) {
                float4 w4 = *(const float4*)(w + f);
                acc += w4.x * px[f] + w4.y * px[f + 1] + w4.z * px[f + 2] + w4.w * px[f + 3];
            }
            pxe[blk * KP + k] = acc;
        } else if (tid >= 128 + KH && tid < 128 + KP) {
            pxe[blk * KP + (tid - 128)] = 0.f;
        }
    } else {
        int hb = blk - BB * NN;         // b*S + t
        int ts = hb % SS, b = hb / SS;
        __shared__ __align__(16) float prc[FF], prb[FF];
        __shared__ __align__(16) float uc[KH], ub[KH];
        float ac1 = ac1p[0], ab1 = ab1p[0];
        float rv = rnn[(b * SS + ts) * FF + tid];
        prc[tid] = prelu_f(rv, ac1);
        prb[tid] = prelu_f(rv, ab1);
        __syncthreads();
        if (tid < KH) {
            const float* wc = Wc1 + tid * FF;
            float ac = 0.f;
#pragma unroll 8
            for (int f = 0; f < FF; f += 4) {
                float4 c4 = *(const float4*)(wc + f);
                ac += c4.x * prc[f] + c4.y * prc[f + 1] + c4.z * prc[f + 2] + c4.w * prc[f + 3];
            }
            uc[tid] = prelu_f(ac + bc1[tid], ac2p[0]);
        } else if (tid >= 128 && tid < 128 + KH) {
            int k = tid - 128;
            const float* wb = Wb1 + k * FF;
            float ab = 0.f;
#pragma unroll 8
            for (int f = 0; f < FF; f += 4) {
                float4 b4 = *(const float4*)(wb + f);
                ab += b4.x * prb[f] + b4.y * prb[f + 1] + b4.z * prb[f + 2] + b4.w * prb[f + 3];
            }
            ub[k] = prelu_f(ab + bb1[k], ab2p[0]);
        }
        __syncthreads();
        if (tid < NCLS) {
            const float* w = Wc2 + tid * KH;
            float acc = bc2[tid];
#pragma unroll
            for (int q = 0; q < KH; q += 4) {
                float4 w4 = *(const float4*)(w + q);
                acc += w4.x * uc[q] + w4.y * uc[q + 1] + w4.z * uc[q + 2] + w4.w * uc[q + 3];
            }
            cls_out[(b * SS + ts) * NCLS + tid] = acc;
        }
        if (tid >= 64 && tid < 66) {
            int o = tid - 64;
            const float* w = Wb2 + o * KH;
            float acc = bb2[o];
#pragma unroll
            for (int q = 0; q < KH; q += 4) {
                float4 w4 = *(const float4*)(w + q);
                acc += w4.x * ub[q] + w4.y * ub[q + 1] + w4.z * ub[q + 2] + w4.w * ub[q + 3];
            }
            bin_out[(b * SS + ts) * 2 + o] = acc;
        }
    }
}

// ---------------- K5: scores (R15 structure, occupancy 2->3) ---------------
#define JT 32
#define JTILES 13
#define NP2 201
#define AP 272          // A-tile row stride in shorts
__global__ __launch_bounds__(256, 3)
void k_scores(const float* __restrict__ cum,
              const short* __restrict__ wfrag,
              const float* __restrict__ pxd, const float* __restrict__ pxe,
              const float* __restrict__ b1p, const float* __restrict__ w2p,
              const float* __restrict__ b2p,
              const float* __restrict__ a1p, const float* __restrict__ a2p,
              float* __restrict__ scores, float* __restrict__ scoresT) {
    int blk = blockIdx.x;
    int jt = blk % JTILES;
    int ipair = (blk / JTILES) % NP2;
    int b = blk / (JTILES * NP2);
    int tid = threadIdx.x;
    float a1 = a1p[0], a2 = a2p[0];
    int jbase = jt * JT;
    int i0 = ipair * 2;
    int i1 = i0 + 1;
    bool has_i1 = (i1 <= SS);
    int i1c = has_i1 ? i1 : i0;

    __shared__ __align__(16) float cish[2][FF];
    __shared__ __align__(16) short dth[2][JT][AP];
    __shared__ float red[2][4][JT];

    cish[0][tid] = cum[(b * NN + i0) * FF + tid];
    cish[1][tid] = cum[(b * NN + i1c) * FF + tid];
    __syncthreads();

    // ---- build both A tiles from ONE cum-row read
    {
        int row = tid >> 3;
        int fb = (tid & 7) * 32;
        int jg = jbase + row;
        int jc = (jg <= SS) ? jg : SS;
        const float* cj = cum + (b * NN + jc) * FF + fb;
        float4 v[8];
#pragma unroll
        for (int c8 = 0; c8 < 4; ++c8) {
            v[2 * c8] = *(const float4*)(cj + c8 * 8);
            v[2 * c8 + 1] = *(const float4*)(cj + c8 * 8 + 4);
        }
#pragma unroll
        for (int ii = 0; ii < 2; ++ii) {
            const float* cio = &cish[ii][0];
#pragma unroll
            for (int c8 = 0; c8 < 4; ++c8) {
                float dv[8] = { v[2*c8].x, v[2*c8].y, v[2*c8].z, v[2*c8].w,
                                v[2*c8+1].x, v[2*c8+1].y, v[2*c8+1].z, v[2*c8+1].w };
                union { short8 s; unsigned short u[8]; } h8;
#pragma unroll
                for (int e = 0; e < 8; ++e) {
                    float d = prelu_f(dv[e] - cio[fb + c8 * 8 + e], a1);
                    h8.u[e] = f2bf(d);
                }
                *(short8*)(&dth[ii][row][fb + c8 * 8]) = h8.s;
            }
        }
    }
    __syncthreads();

    int lane = tid & 63;
    int wv = tid >> 6;
    int quad = lane >> 4;
    int l15 = lane & 15;
    int kt0 = wv * 2, kt1 = wv * 2 + 1;
    bool has1 = (kt1 < 7);

    const short8* wf = (const short8*)wfrag;
    f32x4 acc[2][2][2];
#pragma unroll
    for (int ii = 0; ii < 2; ++ii)
#pragma unroll
        for (int mt = 0; mt < 2; ++mt)
#pragma unroll
            for (int kk = 0; kk < 2; ++kk) acc[ii][mt][kk] = (f32x4){0.f,0.f,0.f,0.f};

#pragma unroll
    for (int ks = 0; ks < 8; ++ks) {
        short8 b0 = wf[((kt0 * 8 + ks) * 4 + quad) * 16 + l15];
        short8 b1v = has1 ? wf[((kt1 * 8 + ks) * 4 + quad) * 16 + l15] : b0;
#pragma unroll
        for (int ii = 0; ii < 2; ++ii) {
#pragma unroll
            for (int mt = 0; mt < 2; ++mt) {
                short8 a = *(const short8*)(&dth[ii][mt * 16 + l15][ks * 32 + quad * 8]);
                acc[ii][mt][0] = __builtin_amdgcn_mfma_f32_16x16x32_bf16(a, b0, acc[ii][mt][0], 0, 0, 0);
                if (has1)
                    acc[ii][mt][1] = __builtin_amdgcn_mfma_f32_16x16x32_bf16(a, b1v, acc[ii][mt][1], 0, 0, 0);
            }
        }
    }

    int kout0 = kt0 * 16 + l15;
    int kout1 = has1 ? (kt1 * 16 + l15) : 0;
    float bb0 = b1p[kout0], bb1v = b1p[kout1];
    float w20 = w2p[kout0];
    float w21 = has1 ? w2p[kout1] : 0.f;

#pragma unroll
    for (int ii = 0; ii < 2; ++ii) {
        int iv = ii ? i1c : i0;
        float pd0 = pxd[(b * NN + iv) * KP + kout0];
        float pd1 = pxd[(b * NN + iv) * KP + kout1];
#pragma unroll
        for (int mt = 0; mt < 2; ++mt) {
#pragma unroll
            for (int r = 0; r < 4; ++r) {
                int m = mt * 16 + quad * 4 + r;
                int jg = jbase + m;
                int jc = (jg <= SS) ? jg : SS;
                float pe0 = pxe[(b * NN + jc) * KP + kout0];
                float pe1 = pxe[(b * NN + jc) * KP + kout1];
                float h0 = acc[ii][mt][0][r] + pd0 + pe0 + bb0;
                float s = w20 * prelu_f(h0, a2);
                float h1 = acc[ii][mt][1][r] + pd1 + pe1 + bb1v;
                s += w21 * prelu_f(h1, a2);
                s += __shfl_xor(s, 1);
                s += __shfl_xor(s, 2);
                s += __shfl_xor(s, 4);
                s += __shfl_xor(s, 8);
                if (l15 == 0) red[ii][wv][m] = s;
            }
        }
    }
    __syncthreads();
    if (tid < 2 * JT) {
        int ii = tid >> 5;
        int jl = tid & 31;
        int jg = jbase + jl;
        int iv = ii ? i1 : i0;
        if (jg <= SS && (ii == 0 || has_i1)) {
            float tot = red[ii][0][jl] + red[ii][1][jl] + red[ii][2][jl] + red[ii][3][jl] + b2p[0];
            scores[(b * NN + iv) * NN + jg] = tot;
            scoresT[(b * NN + jg) * NN + iv] = tot;
        }
    }
}

// ---------------- K7: DP segment search — 4-deep column pipeline -----------
__global__ void k_dp(const float* __restrict__ scoresT, const int* __restrict__ lengths,
                     float* __restrict__ predF, float* __restrict__ prevF) {
    int b = blockIdx.x;
    int lane = threadIdx.x;          // 64 threads = 1 wave
    int len = lengths[b];
    if (lane == 0) prevF[b * NN] = 0.f;

    float blr = 0.f;                 // best[lo + lane]
    float predv = 0.f;

#define LOADCOL(ii) \
    ( ((ii) <= SS && lane < ((ii) - (((ii) > MAXSEG) ? ((ii) - MAXSEG) : 0))) \
        ? scoresT[(b * NN + (ii)) * NN + ((((ii) > MAXSEG) ? ((ii) - MAXSEG) : 0)) + lane] : 0.f )

    float buf0 = LOADCOL(1);
    float buf1 = LOADCOL(2);
    float buf2 = LOADCOL(3);
    float buf3 = LOADCOL(4);

#define DP_STEP(I, BUF) do {                                                  \
        int lo_ = ((I) > MAXSEG) ? ((I) - MAXSEG) : 0;                        \
        int cnt_ = (I) - lo_;                                                 \
        float cand = (lane < cnt_) ? blr + BUF : -INFINITY;                   \
        int idx = lo_ + lane;                                                 \
        for (int off = 32; off; off >>= 1) {                                  \
            float vo = __shfl_down(cand, off);                                \
            int io = __shfl_down(idx, off);                                   \
            if (vo > cand || (vo == cand && io < idx)) { cand = vo; idx = io; } \
        }                                                                     \
        float m_ = __shfl(cand, 0);                                           \
        if (lane == 0) {                                                      \
            prevF[b * NN + (I)] = (float)idx;                                 \
            if ((I) == len) predv = m_;                                       \
        }                                                                     \
        int lon_ = ((I) + 1 > MAXSEG) ? ((I) + 1 - MAXSEG) : 0;               \
        if (lon_ != lo_) blr = __shfl_down(blr, 1);                           \
        if (lane == (I) - lon_) blr = m_;                                     \
    } while (0)

    for (int i = 1; i <= SS; i += 4) {
        DP_STEP(i, buf0);     buf0 = LOADCOL(i + 4);
        DP_STEP(i + 1, buf1); buf1 = LOADCOL(i + 5);
        DP_STEP(i + 2, buf2); buf2 = LOADCOL(i + 6);
        DP_STEP(i + 3, buf3); buf3 = LOADCOL(i + 7);
    }
#undef DP_STEP
#undef LOADCOL
    if (lane == 0) predF[b] = predv;
}

// ---------------- launch ---------------------------------------------------
extern "C" void kernel_launch(void* const* d_in, const int* in_sizes, int n_in,
                              void* d_out, int out_size, void* d_ws, size_t ws_size,
                              hipStream_t stream) {
    const float* x    = (const float*)d_in[0];
    const int* lengths= (const int*)d_in[1];
    const float* Wi_f = (const float*)d_in[2];
    const float* Wh_f = (const float*)d_in[3];
    const float* b_f  = (const float*)d_in[4];
    const float* Wi_b = (const float*)d_in[5];
    const float* Wh_b = (const float*)d_in[6];
    const float* b_b  = (const float*)d_in[7];
    const float* a1   = (const float*)d_in[8];
    const float* W1   = (const float*)d_in[9];
    const float* b1   = (const float*)d_in[10];
    const float* a2   = (const float*)d_in[11];
    const float* W2   = (const float*)d_in[12];
    const float* b2   = (const float*)d_in[13];
    const float* ac1  = (const float*)d_in[14];
    const float* Wc1  = (const float*)d_in[15];
    const float* bc1  = (const float*)d_in[16];
    const float* ac2  = (const float*)d_in[17];
    const float* Wc2  = (const float*)d_in[18];
    const float* bc2  = (const float*)d_in[19];
    const float* ab1  = (const float*)d_in[20];
    const float* Wb1  = (const float*)d_in[21];
    const float* bb1  = (const float*)d_in[22];
    const float* ab2  = (const float*)d_in[23];
    const float* Wb2  = (const float*)d_in[24];
    const float* bb2  = (const float*)d_in[25];

    float* out = (float*)d_out;
    float* scores = out + SCORES_OFF;
    float* cls    = out + CLS_OFF;
    float* bin    = out + BIN_OFF;
    float* pred   = out + PRED_OFF;
    float* prev   = out + PREV_OFF;

    float* ws   = (float*)d_ws;
    float* gx   = ws + WS_GX;
    float* scoresT = ws + WS_GX;     // reuse: gx dead after k_lstm_rec
    float* rnn  = ws + WS_RNN;
    float* cum  = ws + WS_CUM;
    float* pxd  = ws + WS_PXD;
    float* pxe  = ws + WS_PXE;
    float* part = ws + WS_PART;
    float* w2p  = ws + WS_W2P;
    float* b1p  = ws + WS_B1P;
    __half* whp = (__half*)(ws + WS_WHP);
    short* wfrag= (short*)(ws + WS_WFRAG);

    k_lstm_pre<<<PREPBLKS + 4 * SS, 256, 0, stream>>>(x, Wi_f, b_f, Wi_b, b_b, gx,
                                                      W1, W2, b1, Wh_f, Wh_b,
                                                      wfrag, w2p, b1p, whp);
    k_lstm_rec<<<4, 512, 0, stream>>>(whp, gx, rnn);
    k_cum_part<<<BB * NCH, FF, 0, stream>>>(rnn, part);
    k_cum_off<<<BB, FF, 0, stream>>>(part);
    k_cum_write<<<BB * NCH, FF, 0, stream>>>(rnn, part, cum);
    k_pxde_heads<<<BB * NN + BB * SS, 256, 0, stream>>>(rnn, W1, a1, pxd, pxe,
                                                        ac1, Wc1, bc1, ac2, Wc2, bc2,
                                                        ab1, Wb1, bb1, ab2, Wb2, bb2,
                                                        cls, bin);
    k_scores<<<BB * NP2 * JTILES, 256, 0, stream>>>(cum, wfrag, pxd, pxe, b1p, w2p, b2,
                                                    a1, a2, scores, scoresT);
    k_dp<<<BB, 64, 0, stream>>>(scoresT, lengths, pred, prev);
}

// Round 19
// 787.575 us; speedup vs baseline: 1.0254x; 1.0035x over previous
//
#include <hip/hip_runtime.h>
#include <hip/hip_fp16.h>
#include <math.h>

// Problem constants
#define BB 2
#define SS 400
#define II 80
#define HH 128
#define FF 256          // 2*H
#define NN 401          // S+1
#define G4 512          // 4*H
#define MAXSEG 50
#define NCLS 50
#define KH 100          // rows of W1 / Wc1 / Wb1
#define KP 112          // KH padded to 7*16 for MFMA
#define FRAGF 14336     // floats per frag-packed W (28672 shorts)

// d_out layout (floats): scores | cls | bin | pred | prev
#define SCORES_OFF 0
#define CLS_OFF    (BB*NN*NN)
#define BIN_OFF    (CLS_OFF + BB*SS*NCLS)
#define PRED_OFF   (BIN_OFF + BB*SS*2)
#define PREV_OFF   (PRED_OFF + BB)

// workspace layout (float slots)
#define WS_GX      0                          // 819200; dead after rec -> dpcol (51328)
#define WS_RNN     (WS_GX + 4*SS*G4)          // B*S*F
#define WS_CUM     (WS_RNN + BB*SS*FF)        // B*N*F
#define WS_PXD     (WS_CUM + BB*NN*FF)        // B*N*KP
#define WS_PXE     (WS_PXD + BB*NN*KP)
#define WS_PART    (WS_PXE + BB*NN*KP)        // B*16*F
#define WS_W2P     (WS_PART + BB*16*FF)       // KP
#define WS_B1P     (WS_W2P + KP)              // KP
#define WS_WHP     (WS_B1P + KP)              // Wh f16: 65536 floats
#define WS_WFRAGC  (WS_WHP + 65536)
#define WS_WFRAGD  (WS_WFRAGC + FRAGF)
#define WS_WFRAGE  (WS_WFRAGD + FRAGF)
#define WS_WFRAGHC (WS_WFRAGE + FRAGF)
#define WS_WFRAGHB (WS_WFRAGHC + FRAGF)
#define WS_BC1P    (WS_WFRAGHB + FRAGF)       // KP
#define WS_BB1P    (WS_BC1P + KP)             // KP

typedef __attribute__((ext_vector_type(8))) short short8;
typedef __attribute__((ext_vector_type(4))) float f32x4;
typedef _Float16 f16x2 __attribute__((ext_vector_type(2)));

__device__ __forceinline__ float prelu_f(float x, float a) {
    return x >= 0.f ? x : a * x;
}
__device__ __forceinline__ unsigned short f2bf(float x) {
    union { float f; unsigned u; } v; v.f = x;
    unsigned r = v.u + 0x7fffu + ((v.u >> 16) & 1u);   // RNE
    return (unsigned short)(r >> 16);
}
__device__ __forceinline__ float fast_sigmoid(float x) {
    return 1.f / (1.f + __expf(-x));
}
__device__ __forceinline__ float fast_tanh(float x) {
    return 1.f - 2.f / (1.f + __expf(2.f * x));
}
__device__ __forceinline__ float dot2f(unsigned w, unsigned h, float acc) {
#if __has_builtin(__builtin_amdgcn_fdot2)
    union { unsigned u; f16x2 h; } a, b; a.u = w; b.u = h;
    return __builtin_amdgcn_fdot2(a.h, b.h, acc, false);
#else
    union { unsigned u; _Float16 h[2]; } a, b; a.u = w; b.u = h;
    return acc + (float)a.h[0] * (float)b.h[0] + (float)a.h[1] * (float)b.h[1];
#endif
}
__device__ __forceinline__ void barrier_lds() {
    asm volatile("s_waitcnt lgkmcnt(0)\ns_barrier" ::: "memory");
}
__device__ __forceinline__ int fragidx(int k, int f) {
    int kt = k >> 4, l15 = k & 15;
    int ks = f >> 5, quad = (f >> 3) & 3, e = f & 7;
    return ((((kt * 8 + ks) * 4 + quad) * 16) + l15) * 8 + e;
}

// ---------------- K1: fused prep + gx precompute ---------------------------
#define WPACKS (5 * KP)
#define PREPBLKS (WPACKS + G4)
__global__ void k_lstm_pre(const float* __restrict__ x,
                           const float* __restrict__ Wi_f, const float* __restrict__ b_f,
                           const float* __restrict__ Wi_b, const float* __restrict__ b_b,
                           float* __restrict__ gx,
                           const float* __restrict__ W1, const float* __restrict__ W2,
                           const float* __restrict__ b1,
                           const float* __restrict__ Wh_f, const float* __restrict__ Wh_b,
                           const float* __restrict__ Wc1, const float* __restrict__ Wb1,
                           const float* __restrict__ bc1, const float* __restrict__ bb1,
                           short* __restrict__ wfC, short* __restrict__ wfD,
                           short* __restrict__ wfE, short* __restrict__ wfHC,
                           short* __restrict__ wfHB,
                           float* __restrict__ w2p, float* __restrict__ b1p,
                           float* __restrict__ bc1p, float* __restrict__ bb1p,
                           __half* __restrict__ whp) {
    int blk0 = blockIdx.x;
    int tid = threadIdx.x;
    if (blk0 < WPACKS) {
        int which = blk0 / KP;
        int k = blk0 % KP;
        float w = 0.f;
        short* dst = wfC;
        if (which == 0)      { if (k < KH) w = W1[k * (3 * FF) + tid];          dst = wfC; }
        else if (which == 1) { if (k < KH) w = W1[k * (3 * FF) + FF + tid];     dst = wfD; }
        else if (which == 2) { if (k < KH) w = W1[k * (3 * FF) + 2 * FF + tid]; dst = wfE; }
        else if (which == 3) { if (k < KH) w = Wc1[k * FF + tid];               dst = wfHC; }
        else                 { if (k < KH) w = Wb1[k * FF + tid];               dst = wfHB; }
        dst[fragidx(k, tid)] = (short)f2bf(w);
        if (tid == 0) {
            if (which == 0) {
                w2p[k] = (k < KH) ? W2[k] : 0.f;
                b1p[k] = (k < KH) ? b1[k] : 0.f;
            } else if (which == 3) {
                bc1p[k] = (k < KH) ? bc1[k] : 0.f;
            } else if (which == 4) {
                bb1p[k] = (k < KH) ? bb1[k] : 0.f;
            }
        }
        return;
    }
    if (blk0 < PREPBLKS) {
        int g = blk0 - WPACKS;           // 0..511
        int dir = tid >> 7, k = tid & 127;
        const float* Wh = dir ? Wh_b : Wh_f;
        whp[(dir * G4 + g) * HH + k] = (__half)Wh[g * HH + k];
        return;
    }
    int blk = blk0 - PREPBLKS;         // db*S + t
    int t = blk % SS;
    int db = blk / SS;                 // dir*2 + b
    int b = db & 1, dir = db >> 1;
    const float* Wi = dir ? Wi_b : Wi_f;
    const float* bias = dir ? b_b : b_f;
    int xt = dir ? (SS - 1 - t) : t;

    __shared__ __align__(16) float xr[II];
    if (tid < II) xr[tid] = x[(b * SS + xt) * II + tid];
    __syncthreads();

    for (int g = tid; g < G4; g += 256) {
        const float* w = Wi + g * II;
        float acc = bias[g];
#pragma unroll
        for (int i = 0; i < II; i += 4) {
            float4 w4 = *(const float4*)(w + i);
            acc += w4.x * xr[i] + w4.y * xr[i + 1] + w4.z * xr[i + 2] + w4.w * xr[i + 3];
        }
        gx[(db * SS + t) * G4 + g] = acc;
    }
}

// ---------------- K2: recurrent LSTM (measured floor ~275 µs) --------------
__global__ __launch_bounds__(512, 2)
void k_lstm_rec(const __half* __restrict__ whp, const float* __restrict__ gx,
                float* __restrict__ rnn_out) {
    int db = blockIdx.x;
    int b = db & 1, dir = db >> 1;
    int tid = threadIdx.x;          // = gate id g

    uint4 w[16];
    {
        const uint4* wp = (const uint4*)(whp + (dir * G4 + tid) * HH);
#pragma unroll
        for (int c = 0; c < 16; ++c) w[c] = wp[c];
    }

    __shared__ __align__(16) __half hsf[2][144];   // 128 h + pad
    __shared__ float gsh[G4];
    for (int i = tid; i < 2 * 144; i += 512) (&hsf[0][0])[i] = (__half)0.f;
    float c_state = 0.f;
    __syncthreads();

    const float* gxp = gx + db * SS * G4;
    float gcur = gxp[tid];                     // prefetch step 0
    int pb = 0;
    for (int step = 0; step < SS; ++step) {
        float gnext = (step + 1 < SS) ? gxp[(step + 1) * G4 + tid] : 0.f;
        const uint4* hp = (const uint4*)(&hsf[pb][0]);
        float a0 = 0.f, a1 = 0.f, a2 = 0.f, a3 = 0.f;
#pragma unroll
        for (int c = 0; c < 16; ++c) {
            uint4 hq = hp[c];
            a0 = dot2f(w[c].x, hq.x, a0);
            a1 = dot2f(w[c].y, hq.y, a1);
            a2 = dot2f(w[c].z, hq.z, a2);
            a3 = dot2f(w[c].w, hq.w, a3);
        }
        gsh[tid] = (a0 + a1) + (a2 + a3) + gcur;
        barrier_lds();
        if (tid < HH) {
            float gi = gsh[tid], gf = gsh[HH + tid];
            float gg = gsh[2 * HH + tid], go = gsh[3 * HH + tid];
            c_state = fast_sigmoid(gf) * c_state + fast_sigmoid(gi) * fast_tanh(gg);
            float h = fast_sigmoid(go) * fast_tanh(c_state);
            hsf[pb ^ 1][tid] = (__half)h;
            int xt = dir ? (SS - 1 - step) : step;
            rnn_out[(b * SS + xt) * FF + dir * HH + tid] = h;
        }
        barrier_lds();
        pb ^= 1;
        gcur = gnext;
    }
}

// ---------------- K3: cumsum over time (3 passes) --------------------------
#define CHUNK 25
#define NCH 16
__global__ void k_cum_part(const float* __restrict__ rnn, float* __restrict__ part) {
    int blk = blockIdx.x;           // b*NCH + c
    int c = blk % NCH, b = blk / NCH;
    int f = threadIdx.x;
    float s = 0.f;
    for (int r = 0; r < CHUNK; ++r) s += rnn[(b * SS + c * CHUNK + r) * FF + f];
    part[blk * FF + f] = s;
}
__global__ void k_cum_off(float* __restrict__ part) {
    int b = blockIdx.x;
    int f = threadIdx.x;
    float run = 0.f;
    for (int c = 0; c < NCH; ++c) {
        int idx = (b * NCH + c) * FF + f;
        float tmp = part[idx];
        part[idx] = run;
        run += tmp;
    }
}
__global__ void k_cum_write(const float* __restrict__ rnn, const float* __restrict__ part,
                            float* __restrict__ cum) {
    int blk = blockIdx.x;           // b*NCH + c
    int c = blk % NCH, b = blk / NCH;
    int f = threadIdx.x;
    float run = part[blk * FF + f];
    cum[(b * NN + c * CHUNK) * FF + f] = run;
    for (int idx = 1; idx <= CHUNK; ++idx) {
        run += rnn[(b * SS + c * CHUNK + idx - 1) * FF + f];
        cum[(b * NN + c * CHUNK + idx) * FF + f] = run;
    }
}

// ---------------- K4: MFMA mlp — pxde (blk<26) + heads (blk>=26) -----------
#define PXBLKS 26
#define HDBLKS 25
#define AP 272          // A-tile row stride in shorts
#define UCP 116         // uc tile row stride in floats
__global__ __launch_bounds__(256, 2)
void k_mlp(const float* __restrict__ rnn,
           const float* __restrict__ a1p,
           const float* __restrict__ ac1p, const float* __restrict__ ab1p,
           const short* __restrict__ wfD, const short* __restrict__ wfE,
           const short* __restrict__ wfHC, const short* __restrict__ wfHB,
           const float* __restrict__ bc1p, const float* __restrict__ bb1p,
           const float* __restrict__ ac2p, const float* __restrict__ ab2p,
           const float* __restrict__ Wc2, const float* __restrict__ bc2,
           const float* __restrict__ Wb2, const float* __restrict__ bb2,
           float* __restrict__ pxd, float* __restrict__ pxe,
           float* __restrict__ cls_out, float* __restrict__ bin_out) {
    int blk = blockIdx.x;
    int tid = threadIdx.x;
    bool is_px = (blk < PXBLKS);
    int rowbase = is_px ? blk * 32 : (blk - PXBLKS) * 32;
    int nrows_tot = is_px ? BB * NN : BB * SS;

    __shared__ __align__(16) short dth[2][32][AP];
    __shared__ float ucsh[2][32][UCP];

    // ---- build A tiles (rows = data rows)
    {
        int row = tid >> 3;
        int fb = (tid & 7) * 32;
        int rg = rowbase + row;
        float src[32];
        if (is_px) {
            float a1 = a1p[0];
            int b = rg / NN, n = rg % NN;
            bool valid = (rg < nrows_tot) && (n > 0);
            const float* sp = valid ? (rnn + (b * SS + n - 1) * FF + fb) : nullptr;
#pragma unroll
            for (int c4 = 0; c4 < 8; ++c4) {
                float4 v = valid ? *(const float4*)(sp + c4 * 4) : make_float4(0,0,0,0);
                src[c4*4] = v.x; src[c4*4+1] = v.y; src[c4*4+2] = v.z; src[c4*4+3] = v.w;
            }
            union { short8 s; unsigned short u[8]; } h8;
#pragma unroll
            for (int c8 = 0; c8 < 4; ++c8) {
#pragma unroll
                for (int e = 0; e < 8; ++e) h8.u[e] = f2bf(prelu_f(src[c8*8+e], a1));
                *(short8*)(&dth[0][row][fb + c8 * 8]) = h8.s;
            }
        } else {
            float ac1 = ac1p[0], ab1 = ab1p[0];
            bool valid = (rg < nrows_tot);
            const float* sp = valid ? (rnn + rg * FF + fb) : nullptr;
#pragma unroll
            for (int c4 = 0; c4 < 8; ++c4) {
                float4 v = valid ? *(const float4*)(sp + c4 * 4) : make_float4(0,0,0,0);
                src[c4*4] = v.x; src[c4*4+1] = v.y; src[c4*4+2] = v.z; src[c4*4+3] = v.w;
            }
            union { short8 s; unsigned short u[8]; } hc, hb;
#pragma unroll
            for (int c8 = 0; c8 < 4; ++c8) {
#pragma unroll
                for (int e = 0; e < 8; ++e) {
                    hc.u[e] = f2bf(prelu_f(src[c8*8+e], ac1));
                    hb.u[e] = f2bf(prelu_f(src[c8*8+e], ab1));
                }
                *(short8*)(&dth[0][row][fb + c8 * 8]) = hc.s;
                *(short8*)(&dth[1][row][fb + c8 * 8]) = hb.s;
            }
        }
    }
    __syncthreads();

    int lane = tid & 63;
    int wv = tid >> 6;
    int quad = lane >> 4;
    int l15 = lane & 15;
    int kt0 = wv * 2, kt1 = wv * 2 + 1;
    bool has1 = (kt1 < 7);

    const short8* wp0 = (const short8*)(is_px ? wfD : wfHC);
    const short8* wp1 = (const short8*)(is_px ? wfE : wfHB);

    // acc[path][mt][kt]
    f32x4 acc[2][2][2];
#pragma unroll
    for (int p = 0; p < 2; ++p)
#pragma unroll
        for (int mt = 0; mt < 2; ++mt)
#pragma unroll
            for (int kk = 0; kk < 2; ++kk) acc[p][mt][kk] = (f32x4){0.f,0.f,0.f,0.f};

#pragma unroll
    for (int ks = 0; ks < 8; ++ks) {
        short8 b00 = wp0[((kt0 * 8 + ks) * 4 + quad) * 16 + l15];
        short8 b01 = has1 ? wp0[((kt1 * 8 + ks) * 4 + quad) * 16 + l15] : b00;
        short8 b10 = wp1[((kt0 * 8 + ks) * 4 + quad) * 16 + l15];
        short8 b11 = has1 ? wp1[((kt1 * 8 + ks) * 4 + quad) * 16 + l15] : b10;
#pragma unroll
        for (int mt = 0; mt < 2; ++mt) {
            short8 a0 = *(const short8*)(&dth[0][mt * 16 + l15][ks * 32 + quad * 8]);
            short8 a1v = is_px ? a0
                       : *(const short8*)(&dth[1][mt * 16 + l15][ks * 32 + quad * 8]);
            acc[0][mt][0] = __builtin_amdgcn_mfma_f32_16x16x32_bf16(a0, b00, acc[0][mt][0], 0, 0, 0);
            acc[1][mt][0] = __builtin_amdgcn_mfma_f32_16x16x32_bf16(a1v, b10, acc[1][mt][0], 0, 0, 0);
            if (has1) {
                acc[0][mt][1] = __builtin_amdgcn_mfma_f32_16x16x32_bf16(a0, b01, acc[0][mt][1], 0, 0, 0);
                acc[1][mt][1] = __builtin_amdgcn_mfma_f32_16x16x32_bf16(a1v, b11, acc[1][mt][1], 0, 0, 0);
            }
        }
    }

    int kout0 = kt0 * 16 + l15;
    int kout1 = has1 ? (kt1 * 16 + l15) : 0;

    if (is_px) {
#pragma unroll
        for (int mt = 0; mt < 2; ++mt) {
#pragma unroll
            for (int r = 0; r < 4; ++r) {
                int m = mt * 16 + quad * 4 + r;
                int rg = rowbase + m;
                if (rg < nrows_tot) {
                    pxd[rg * KP + kout0] = acc[0][mt][0][r];
                    pxe[rg * KP + kout0] = acc[1][mt][0][r];
                    if (has1) {
                        pxd[rg * KP + kout1] = acc[0][mt][1][r];
                        pxe[rg * KP + kout1] = acc[1][mt][1][r];
                    }
                }
            }
        }
        return;
    }

    // heads: layer1 activation -> LDS, then layer2 matvecs
    float bc0 = bc1p[kout0], bc1v = bc1p[kout1];
    float bb0 = bb1p[kout0], bb1v = bb1p[kout1];
    float ac2 = ac2p[0], ab2 = ab2p[0];
#pragma unroll
    for (int mt = 0; mt < 2; ++mt) {
#pragma unroll
        for (int r = 0; r < 4; ++r) {
            int m = mt * 16 + quad * 4 + r;
            ucsh[0][m][kout0] = prelu_f(acc[0][mt][0][r] + bc0, ac2);
            ucsh[1][m][kout0] = prelu_f(acc[1][mt][0][r] + bb0, ab2);
            if (has1) {
                ucsh[0][m][kout1] = prelu_f(acc[0][mt][1][r] + bc1v, ac2);
                ucsh[1][m][kout1] = prelu_f(acc[1][mt][1][r] + bb1v, ab2);
            }
        }
    }
    __syncthreads();
    {
        int row = tid >> 3;
        int oc = tid & 7;
        int rg = rowbase + row;
        bool valid = (rg < nrows_tot);
        for (int o = oc; o < NCLS; o += 8) {
            float s = bc2[o];
            const float* w = Wc2 + o * KH;
#pragma unroll 4
            for (int k = 0; k < KH; ++k) s += w[k] * ucsh[0][row][k];
            if (valid) cls_out[rg * NCLS + o] = s;
        }
        // bin: 32 rows x 2 outputs = 64 work items (tid < 64 covers all;
        // R18's extra tid<128 branch read ucsh rows 32..47 OOB -> NaN)
        if (tid < 64) {
            int row2 = tid >> 1, o = tid & 1;
            int rg2 = rowbase + row2;
            float s = bb2[o];
            const float* w = Wb2 + o * KH;
#pragma unroll 4
            for (int k = 0; k < KH; ++k) s += w[k] * ucsh[1][row2][k];
            if (rg2 < nrows_tot) bin_out[rg2 * 2 + o] = s;
        }
    }
}

// ---------------- K5: scores (R15 structure; dpcol instead of scoresT) -----
#define JT 32
#define JTILES 13
#define NP2 201
__global__ __launch_bounds__(256, 3)
void k_scores(const float* __restrict__ cum,
              const short* __restrict__ wfrag,
              const float* __restrict__ pxd, const float* __restrict__ pxe,
              const float* __restrict__ b1p, const float* __restrict__ w2p,
              const float* __restrict__ b2p,
              const float* __restrict__ a1p, const float* __restrict__ a2p,
              float* __restrict__ scores, float* __restrict__ dpcol) {
    int blk = blockIdx.x;
    int jt = blk % JTILES;
    int ipair = (blk / JTILES) % NP2;
    int b = blk / (JTILES * NP2);
    int tid = threadIdx.x;
    float a1 = a1p[0], a2 = a2p[0];
    int jbase = jt * JT;
    int i0 = ipair * 2;
    int i1 = i0 + 1;
    bool has_i1 = (i1 <= SS);
    int i1c = has_i1 ? i1 : i0;

    __shared__ __align__(16) float cish[2][FF];
    __shared__ __align__(16) short dth[2][JT][AP];
    __shared__ float red[2][4][JT];

    cish[0][tid] = cum[(b * NN + i0) * FF + tid];
    cish[1][tid] = cum[(b * NN + i1c) * FF + tid];
    __syncthreads();

    {
        int row = tid >> 3;
        int fb = (tid & 7) * 32;
        int jg = jbase + row;
        int jc = (jg <= SS) ? jg : SS;
        const float* cj = cum + (b * NN + jc) * FF + fb;
        float4 v[8];
#pragma unroll
        for (int c8 = 0; c8 < 4; ++c8) {
            v[2 * c8] = *(const float4*)(cj + c8 * 8);
            v[2 * c8 + 1] = *(const float4*)(cj + c8 * 8 + 4);
        }
#pragma unroll
        for (int ii = 0; ii < 2; ++ii) {
            const float* cio = &cish[ii][0];
#pragma unroll
            for (int c8 = 0; c8 < 4; ++c8) {
                float dv[8] = { v[2*c8].x, v[2*c8].y, v[2*c8].z, v[2*c8].w,
                                v[2*c8+1].x, v[2*c8+1].y, v[2*c8+1].z, v[2*c8+1].w };
                union { short8 s; unsigned short u[8]; } h8;
#pragma unroll
                for (int e = 0; e < 8; ++e) {
                    float d = prelu_f(dv[e] - cio[fb + c8 * 8 + e], a1);
                    h8.u[e] = f2bf(d);
                }
                *(short8*)(&dth[ii][row][fb + c8 * 8]) = h8.s;
            }
        }
    }
    __syncthreads();

    int lane = tid & 63;
    int wv = tid >> 6;
    int quad = lane >> 4;
    int l15 = lane & 15;
    int kt0 = wv * 2, kt1 = wv * 2 + 1;
    bool has1 = (kt1 < 7);

    const short8* wf = (const short8*)wfrag;
    f32x4 acc[2][2][2];
#pragma unroll
    for (int ii = 0; ii < 2; ++ii)
#pragma unroll
        for (int mt = 0; mt < 2; ++mt)
#pragma unroll
            for (int kk = 0; kk < 2; ++kk) acc[ii][mt][kk] = (f32x4){0.f,0.f,0.f,0.f};

#pragma unroll
    for (int ks = 0; ks < 8; ++ks) {
        short8 b0 = wf[((kt0 * 8 + ks) * 4 + quad) * 16 + l15];
        short8 b1v = has1 ? wf[((kt1 * 8 + ks) * 4 + quad) * 16 + l15] : b0;
#pragma unroll
        for (int ii = 0; ii < 2; ++ii) {
#pragma unroll
            for (int mt = 0; mt < 2; ++mt) {
                short8 a = *(const short8*)(&dth[ii][mt * 16 + l15][ks * 32 + quad * 8]);
                acc[ii][mt][0] = __builtin_amdgcn_mfma_f32_16x16x32_bf16(a, b0, acc[ii][mt][0], 0, 0, 0);
                if (has1)
                    acc[ii][mt][1] = __builtin_amdgcn_mfma_f32_16x16x32_bf16(a, b1v, acc[ii][mt][1], 0, 0, 0);
            }
        }
    }

    int kout0 = kt0 * 16 + l15;
    int kout1 = has1 ? (kt1 * 16 + l15) : 0;
    float bb0 = b1p[kout0], bb1v = b1p[kout1];
    float w20 = w2p[kout0];
    float w21 = has1 ? w2p[kout1] : 0.f;

#pragma unroll
    for (int ii = 0; ii < 2; ++ii) {
        int iv = ii ? i1c : i0;
        float pd0 = pxd[(b * NN + iv) * KP + kout0];
        float pd1 = pxd[(b * NN + iv) * KP + kout1];
#pragma unroll
        for (int mt = 0; mt < 2; ++mt) {
#pragma unroll
            for (int r = 0; r < 4; ++r) {
                int m = mt * 16 + quad * 4 + r;
                int jg = jbase + m;
                int jc = (jg <= SS) ? jg : SS;
                float pe0 = pxe[(b * NN + jc) * KP + kout0];
                float pe1 = pxe[(b * NN + jc) * KP + kout1];
                float h0 = acc[ii][mt][0][r] + pd0 + pe0 + bb0;
                float s = w20 * prelu_f(h0, a2);
                float h1 = acc[ii][mt][1][r] + pd1 + pe1 + bb1v;
                s += w21 * prelu_f(h1, a2);
                s += __shfl_xor(s, 1);
                s += __shfl_xor(s, 2);
                s += __shfl_xor(s, 4);
                s += __shfl_xor(s, 8);
                if (l15 == 0) red[ii][wv][m] = s;
            }
        }
    }
    __syncthreads();
    if (tid < 2 * JT) {
        int ii = tid >> 5;
        int jl = tid & 31;
        int jg = jbase + jl;
        int iv = ii ? i1 : i0;
        if (jg <= SS && (ii == 0 || has_i1)) {
            float tot = red[ii][0][jl] + red[ii][1][jl] + red[ii][2][jl] + red[ii][3][jl] + b2p[0];
            scores[(b * NN + iv) * NN + jg] = tot;
            int d = jg - iv;
            if (d >= 1 && d <= MAXSEG) {
                int lo = (jg > MAXSEG) ? (jg - MAXSEG) : 0;
                dpcol[(b * NN + jg) * 64 + (iv - lo)] = tot;
            }
        }
    }
}

// ---------------- K7: DP — compact dpcol + 4-deep pipeline -----------------
__global__ void k_dp(const float* __restrict__ dpcol, const int* __restrict__ lengths,
                     float* __restrict__ predF, float* __restrict__ prevF) {
    int b = blockIdx.x;
    int lane = threadIdx.x;          // 64 threads = 1 wave
    int len = lengths[b];
    if (lane == 0) prevF[b * NN] = 0.f;

    float blr = 0.f;                 // best[lo + lane]
    float predv = 0.f;

#define LOADCOL(ii) \
    ( ((ii) <= SS && lane < ((ii) - (((ii) > MAXSEG) ? ((ii) - MAXSEG) : 0))) \
        ? dpcol[(b * NN + (ii)) * 64 + lane] : 0.f )

    float buf0 = LOADCOL(1);
    float buf1 = LOADCOL(2);
    float buf2 = LOADCOL(3);
    float buf3 = LOADCOL(4);

#define DP_STEP(I, BUF) do {                                                  \
        int lo_ = ((I) > MAXSEG) ? ((I) - MAXSEG) : 0;                        \
        int cnt_ = (I) - lo_;                                                 \
        float cand = (lane < cnt_) ? blr + BUF : -INFINITY;                   \
        int idx = lo_ + lane;                                                 \
        for (int off = 32; off; off >>= 1) {                                  \
            float vo = __shfl_down(cand, off);                                \
            int io = __shfl_down(idx, off);                                   \
            if (vo > cand || (vo == cand && io < idx)) { cand = vo; idx = io; } \
        }                                                                     \
        float m_ = __shfl(cand, 0);                                           \
        if (lane == 0) {                                                      \
            prevF[b * NN + (I)] = (float)idx;                                 \
            if ((I) == len) predv = m_;                                       \
        }                                                                     \
        int lon_ = ((I) + 1 > MAXSEG) ? ((I) + 1 - MAXSEG) : 0;               \
        if (lon_ != lo_) blr = __shfl_down(blr, 1);                           \
        if (lane == (I) - lon_) blr = m_;                                     \
    } while (0)

    for (int i = 1; i <= SS; i += 4) {
        DP_STEP(i, buf0);     buf0 = LOADCOL(i + 4);
        DP_STEP(i + 1, buf1); buf1 = LOADCOL(i + 5);
        DP_STEP(i + 2, buf2); buf2 = LOADCOL(i + 6);
        DP_STEP(i + 3, buf3); buf3 = LOADCOL(i + 7);
    }
#undef DP_STEP
#undef LOADCOL
    if (lane == 0) predF[b] = predv;
}

// ---------------- launch ---------------------------------------------------
extern "C" void kernel_launch(void* const* d_in, const int* in_sizes, int n_in,
                              void* d_out, int out_size, void* d_ws, size_t ws_size,
                              hipStream_t stream) {
    const float* x    = (const float*)d_in[0];
    const int* lengths= (const int*)d_in[1];
    const float* Wi_f = (const float*)d_in[2];
    const float* Wh_f = (const float*)d_in[3];
    const float* b_f  = (const float*)d_in[4];
    const float* Wi_b = (const float*)d_in[5];
    const float* Wh_b = (const float*)d_in[6];
    const float* b_b  = (const float*)d_in[7];
    const float* a1   = (const float*)d_in[8];
    const float* W1   = (const float*)d_in[9];
    const float* b1   = (const float*)d_in[10];
    const float* a2   = (const float*)d_in[11];
    const float* W2   = (const float*)d_in[12];
    const float* b2   = (const float*)d_in[13];
    const float* ac1  = (const float*)d_in[14];
    const float* Wc1  = (const float*)d_in[15];
    const float* bc1  = (const float*)d_in[16];
    const float* ac2  = (const float*)d_in[17];
    const float* Wc2  = (const float*)d_in[18];
    const float* bc2  = (const float*)d_in[19];
    const float* ab1  = (const float*)d_in[20];
    const float* Wb1  = (const float*)d_in[21];
    const float* bb1  = (const float*)d_in[22];
    const float* ab2  = (const float*)d_in[23];
    const float* Wb2  = (const float*)d_in[24];
    const float* bb2  = (const float*)d_in[25];

    float* out = (float*)d_out;
    float* scores = out + SCORES_OFF;
    float* cls    = out + CLS_OFF;
    float* bin    = out + BIN_OFF;
    float* pred   = out + PRED_OFF;
    float* prev   = out + PREV_OFF;

    float* ws    = (float*)d_ws;
    float* gx    = ws + WS_GX;
    float* dpcol = ws + WS_GX;       // reuse: gx dead after k_lstm_rec
    float* rnn   = ws + WS_RNN;
    float* cum   = ws + WS_CUM;
    float* pxd   = ws + WS_PXD;
    float* pxe   = ws + WS_PXE;
    float* part  = ws + WS_PART;
    float* w2p   = ws + WS_W2P;
    float* b1p   = ws + WS_B1P;
    __half* whp  = (__half*)(ws + WS_WHP);
    short* wfC   = (short*)(ws + WS_WFRAGC);
    short* wfD   = (short*)(ws + WS_WFRAGD);
    short* wfE   = (short*)(ws + WS_WFRAGE);
    short* wfHC  = (short*)(ws + WS_WFRAGHC);
    short* wfHB  = (short*)(ws + WS_WFRAGHB);
    float* bc1p  = ws + WS_BC1P;
    float* bb1p  = ws + WS_BB1P;

    k_lstm_pre<<<PREPBLKS + 4 * SS, 256, 0, stream>>>(x, Wi_f, b_f, Wi_b, b_b, gx,
                                                      W1, W2, b1, Wh_f, Wh_b,
                                                      Wc1, Wb1, bc1, bb1,
                                                      wfC, wfD, wfE, wfHC, wfHB,
                                                      w2p, b1p, bc1p, bb1p, whp);
    k_lstm_rec<<<4, 512, 0, stream>>>(whp, gx, rnn);
    k_cum_part<<<BB * NCH, FF, 0, stream>>>(rnn, part);
    k_cum_off<<<BB, FF, 0, stream>>>(part);
    k_cum_write<<<BB * NCH, FF, 0, stream>>>(rnn, part, cum);
    k_mlp<<<PXBLKS + HDBLKS, 256, 0, stream>>>(rnn, a1, ac1, ab1,
                                               wfD, wfE, wfHC, wfHB,
                                               bc1p, bb1p, ac2, ab2,
                                               Wc2, bc2, Wb2, bb2,
                                               pxd, pxe, cls, bin);
    k_scores<<<BB * NP2 * JTILES, 256, 0, stream>>>(cum, wfC, pxd, pxe, b1p, w2p, b2,
                                                    a1, a2, scores, dpcol);
    k_dp<<<BB, 64, 0, stream>>>(dpcol, lengths, pred, prev);
}